// Round 18
// baseline (177.772 us; speedup 1.0000x reference)
//
#include <hip/hip_runtime.h>
#include <stdint.h>

// ============================================================================
// Motion_Relation_Mining — bit-exact replication of the JAX (CPU) reference.
//
// FROZEN (verified passing R0-R17, absmax 0.0): all f32 op sequences,
// NAN_POLICY_A, FMA-tanh, sequential reduce orders, selection key
// (enc(value)<<32)|~idx i.e. (value desc, index asc).
//
// R2: two-stage reductions replaced contended global atomics.
// R3: k_corr parallelized (scratch -> LDS, logs 100-wide).
// R4 (FAILED): ballot match-any — unroll spilled enc[] to scratch.
// R8: block-wide bitwise threshold search — barrier convoy (97us).
// R9: wave-autonomous threshold search (shfl-only, zero barriers).
// R10: k_mag_all (x read once), non-atomic hist partials, fused corr.
// R11 (FAILED): fusing top64 into the 28-block kernel throttled it.
// R12-R16: radix-select merge pipeline (184.7us).
// R17: 7 -> 5 kernels (mm_reduce folded into hist; mag+top64 fused as
//      k_magtop). 171.6us. Node overhead ~6.5us each; 5-stage chain is
//      dependency-minimal.
// R18: block-stage-2 filter in k_magtop — wave top-64s go to LDS; wave 0
//      finds Tb = 64th-largest of the union (= of the block's 4096, since
//      block-top64 is contained in the union) and emits only enc>=Tb.
//      Candidates/bf: 4096 -> ~1024 (4x less merge phase-2 + compaction;
//      retires the candk at-cap clamp hazard). merge_graph reverts to the
//      16-range R16 structure. Same key/tie semantics -> bit-exact.
// ============================================================================

typedef unsigned int u32;
typedef unsigned long long u64;

// sizes
#define BB 4
#define TT 8
#define CC 16
#define HWN 65536              // H*W
#define NF 7
#define FRAME 1048576LL        // C*H*W
#define NELF 7340032.0f        // nf*C*H*W per batch (exact in f32)
#define NPAIR 28
#define SEG 65536

// ws layout (bytes)
#define WS_CORR 128            // float[4]
#define WS_WCNT 144            // u32[28*16] per-block candidate counts
#define WS_MMPART 16384        // u32[2048][6] = 48 KiB (minmax partials)
#define WS_CAND   (16384 + 65536)             // u64[28][2048] = 448 KiB
#define WS_HISTC  (16384 + 65536 + 2097152)   // u32[2048][300] = 2.4 MiB
#define WS_NEED (16384 + 28LL*65536*4)

__device__ __forceinline__ u32 encf(float f) {
  u32 u = __float_as_uint(f);
  return (u & 0x80000000u) ? ~u : (u | 0x80000000u);
}
__device__ __forceinline__ float decf(u32 e) {
  u32 u = (e & 0x80000000u) ? (e ^ 0x80000000u) : ~e;
  return __uint_as_float(u);
}

// ---- single pass over frames: per-batch min/max of x_t, x_t1, x_t*x_t1.
// float4 loads; min/max order-free; product elementwise -> exact.
__global__ void k_minmax_pass(const float* __restrict__ x, u32* __restrict__ part) {
  const int blk = blockIdx.x;            // 2048 blocks: 512 per batch
  const int b = blk >> 9;
  const long long w0 = (long long)(blk & 511) * 2048;
  const int tid = threadIdx.x;
  u32 mn0 = 0xFFFFFFFFu, mx0 = 0u, mn1 = 0xFFFFFFFFu, mx1 = 0u,
      mnp = 0xFFFFFFFFu, mxp = 0u;
  float4 pv0, pv1;
  for (int t = 0; t < 8; ++t) {
    const float4* fp = (const float4*)(x + ((long long)(b * TT + t)) * FRAME + w0);
    float4 v0 = fp[tid];
    float4 v1 = fp[tid + 256];
#define MM_COMP(vc, pc)                                                     \
    {                                                                       \
      u32 ev = encf(vc);                                                    \
      if (t < 7) { mn0 = min(mn0, ev); mx0 = max(mx0, ev); }                \
      if (t > 0) {                                                          \
        mn1 = min(mn1, ev); mx1 = max(mx1, ev);                             \
        u32 ep = encf(__fmul_rn(pc, vc));                                   \
        mnp = min(mnp, ep); mxp = max(mxp, ep);                             \
      }                                                                     \
    }
    MM_COMP(v0.x, pv0.x) MM_COMP(v0.y, pv0.y) MM_COMP(v0.z, pv0.z) MM_COMP(v0.w, pv0.w)
    MM_COMP(v1.x, pv1.x) MM_COMP(v1.y, pv1.y) MM_COMP(v1.z, pv1.z) MM_COMP(v1.w, pv1.w)
#undef MM_COMP
    pv0 = v0; pv1 = v1;
  }
  __shared__ u32 sm[6][256];
  sm[0][tid] = mn0; sm[1][tid] = mx0; sm[2][tid] = mn1;
  sm[3][tid] = mx1; sm[4][tid] = mnp; sm[5][tid] = mxp;
  __syncthreads();
  for (int st = 128; st > 0; st >>= 1) {
    if (tid < st) {
      sm[0][tid] = min(sm[0][tid], sm[0][tid + st]);
      sm[1][tid] = max(sm[1][tid], sm[1][tid + st]);
      sm[2][tid] = min(sm[2][tid], sm[2][tid + st]);
      sm[3][tid] = max(sm[3][tid], sm[3][tid + st]);
      sm[4][tid] = min(sm[4][tid], sm[4][tid + st]);
      sm[5][tid] = max(sm[5][tid], sm[5][tid + st]);
    }
    __syncthreads();
  }
  if (tid == 0) {
    u32* o = part + blk * 6;
    o[0] = sm[0][0]; o[1] = sm[1][0]; o[2] = sm[2][0];
    o[3] = sm[3][0]; o[4] = sm[4][0]; o[5] = sm[5][0];
  }
}

__device__ __forceinline__ int bin_of(float v, float vmin, float den) {
  float tt = __fsub_rn(v, vmin);
  float q = __fdiv_rn(tt, den);
  float z = __fmul_rn(q, 100.0f);
  z = fminf(fmaxf(z, 0.0f), 99.0f);
  return (int)z;
}

// ---- single pass over frames. Embeds the mm reduction (redundant 48KB
// L2-hot reduce/block; order-free -> bit-identical mn/den). float4 loads +
// 32-way lane-replicated LDS sub-histograms, non-atomic private flush.
__global__ void k_hist_pass(const float* __restrict__ x, const u32* __restrict__ part,
                            u32* __restrict__ histc) {
  __shared__ u32 h[300 * 32];            // reused: first as [6][256] mm scratch
  const int tid = threadIdx.x;
  {
    u32 a0 = 0xFFFFFFFFu, a1 = 0u, a2 = 0xFFFFFFFFu, a3 = 0u, a4 = 0xFFFFFFFFu, a5 = 0u;
    for (int p = tid; p < 2048; p += 256) {
      const u32* q = part + p * 6;
      a0 = min(a0, q[0]); a1 = max(a1, q[1]);
      a2 = min(a2, q[2]); a3 = max(a3, q[3]);
      a4 = min(a4, q[4]); a5 = max(a5, q[5]);
    }
    h[tid] = a0; h[256 + tid] = a1; h[512 + tid] = a2;
    h[768 + tid] = a3; h[1024 + tid] = a4; h[1280 + tid] = a5;
  }
  __syncthreads();
  for (int st = 128; st > 0; st >>= 1) {
    if (tid < st) {
      h[tid] = min(h[tid], h[tid + st]);
      h[256 + tid] = max(h[256 + tid], h[256 + tid + st]);
      h[512 + tid] = min(h[512 + tid], h[512 + tid + st]);
      h[768 + tid] = max(h[768 + tid], h[768 + tid + st]);
      h[1024 + tid] = min(h[1024 + tid], h[1024 + tid + st]);
      h[1280 + tid] = max(h[1280 + tid], h[1280 + tid + st]);
    }
    __syncthreads();
  }
  const float mn_t = decf(h[0]);
  const float den_t = __fsub_rn(decf(h[256]), decf(h[0]));
  const float mn_1 = decf(h[512]);
  const float den_1 = __fsub_rn(decf(h[768]), decf(h[512]));
  const float mn_p = decf(h[1024]);
  const float den_p = __fsub_rn(decf(h[1280]), decf(h[1024]));
  __syncthreads();
  for (int i = tid; i < 9600; i += 256) h[i] = 0u;
  __syncthreads();
  const int blk = blockIdx.x;
  const int b = blk >> 9;
  const long long w0 = (long long)(blk & 511) * 2048;
  const int sub = tid & 31;
  float4 pv0, pv1;
  for (int t = 0; t < 8; ++t) {
    const float4* fp = (const float4*)(x + ((long long)(b * TT + t)) * FRAME + w0);
    float4 v0 = fp[tid];
    float4 v1 = fp[tid + 256];
#define HH_COMP(vc, pc)                                                       \
    {                                                                         \
      if (t < 7) atomicAdd(&h[bin_of(vc, mn_t, den_t) * 32 + sub], 1u);       \
      if (t > 0) {                                                            \
        atomicAdd(&h[(100 + bin_of(vc, mn_1, den_1)) * 32 + sub], 1u);        \
        float p = __fmul_rn(pc, vc);                                          \
        atomicAdd(&h[(200 + bin_of(p, mn_p, den_p)) * 32 + sub], 1u);         \
      }                                                                       \
    }
    HH_COMP(v0.x, pv0.x) HH_COMP(v0.y, pv0.y) HH_COMP(v0.z, pv0.z) HH_COMP(v0.w, pv0.w)
    HH_COMP(v1.x, pv1.x) HH_COMP(v1.y, pv1.y) HH_COMP(v1.z, pv1.z) HH_COMP(v1.w, pv1.w)
#undef HH_COMP
    pv0 = v0; pv1 = v1;
  }
  __syncthreads();
  u32* dst = histc + blk * 300;
  for (int i = tid; i < 300; i += 256) {
    u32 s = 0;
#pragma unroll
    for (int c = 0; c < 32; ++c)
      s += h[i * 32 + ((c + i) & 31)];   // rotated: conflict-free banks
    dst[i] = s;
  }
}

// Eigen/XLA fast-tanh rational interpolant (FMA form) — FROZEN
__device__ float tanh_emul(float a) {
  const float kClamp = 7.90531110763549805f;
  float xx = fminf(fmaxf(a, -kClamp), kClamp);
  float x2 = __fmul_rn(xx, xx);
  float p = __fmaf_rn(x2, -2.76076847742355e-16f, 2.00018790482477e-13f);
  p = __fmaf_rn(x2, p, -8.60467152213735e-11f);
  p = __fmaf_rn(x2, p, 5.12229709037114e-08f);
  p = __fmaf_rn(x2, p, 1.48572235717979e-05f);
  p = __fmaf_rn(x2, p, 6.37261928875436e-04f);
  p = __fmaf_rn(x2, p, 4.89352455891786e-03f);
  p = __fmul_rn(xx, p);
  float q = __fmaf_rn(x2, 1.19825839466702e-06f, 1.18534705686654e-04f);
  q = __fmaf_rn(x2, q, 2.26843463243900e-03f);
  q = __fmaf_rn(x2, q, 4.89352518554385e-03f);
  float r = __fdiv_rn(p, q);
  if (fabsf(a) < 0.0004f) r = a;
  return r;
}

// ---- per-batch: sum 512 partial histograms (8-way ILP, exact ints),
// then mi/corr with FROZEN sequential chains on thread 0.
__global__ void __launch_bounds__(256) k_corr(const u32* __restrict__ histc,
                                              float* __restrict__ corr) {
  const int b = blockIdx.x;
  const int tid = threadIdx.x;
  __shared__ u32 shist[300];
  __shared__ float shx[100], shx1[100], sterm[100];
  __shared__ float ssum[3];
  for (int i = tid; i < 300; i += 256) {
    const u32* src = histc + (long long)(b * 512) * 300 + i;
    u32 s0 = 0, s1 = 0, s2 = 0, s3 = 0, s4 = 0, s5 = 0, s6 = 0, s7 = 0;
    for (int c = 0; c < 512; c += 8) {
      s0 += src[(c + 0) * 300]; s1 += src[(c + 1) * 300];
      s2 += src[(c + 2) * 300]; s3 += src[(c + 3) * 300];
      s4 += src[(c + 4) * 300]; s5 += src[(c + 5) * 300];
      s6 += src[(c + 6) * 300]; s7 += src[(c + 7) * 300];
    }
    shist[i] = ((s0 + s1) + (s2 + s3)) + ((s4 + s5) + (s6 + s7));
  }
  __syncthreads();
  const u32* HX = shist;
  const u32* HX1 = shist + 100;
  const u32* HJ = shist + 200;
  if (tid < 100) {
    shx[tid] = __fdiv_rn((float)HX[tid], NELF);
    shx1[tid] = __fdiv_rn((float)HX1[tid], NELF);
  }
  __syncthreads();
  if (tid == 0) {
    float Sj = 0.0f;
    for (int i = 0; i < 100; ++i) Sj = __fadd_rn(Sj, (float)HJ[i]);
    float Sx = 0.0f, Sx1 = 0.0f;
    for (int i = 0; i < 100; ++i) Sx = __fadd_rn(Sx, shx[i]);
    for (int i = 0; i < 100; ++i) Sx1 = __fadd_rn(Sx1, shx1[i]);
    ssum[0] = Sj; ssum[1] = Sx; ssum[2] = Sx1;
  }
  __syncthreads();
  if (tid < 100) {
    float Sj = ssum[0], Sx = ssum[1], Sx1 = ssum[2];
    float pj = __fdiv_rn((float)HJ[tid], Sj);
    float px = __fdiv_rn(shx[tid], Sx);
    float px1 = __fdiv_rn(shx1[tid], Sx1);
    float la = (float)log((double)__fadd_rn(pj, 1e-10f));
    float lb = (float)log((double)__fadd_rn(__fmul_rn(px, px1), 1e-10f));
    sterm[tid] = __fmul_rn(pj, __fsub_rn(la, lb));
  }
  __syncthreads();
  if (tid == 0) {
    float mi = 0.0f;
    for (int i = 0; i < 100; ++i) mi = __fadd_rn(mi, sterm[i]);
    float lm = (float)log((double)mi);
    float th = tanh_emul(lm);
    float num = (float)exp(0.8);
    corr[b] = __fdiv_rn(num, th);
  }
}

// ---- fused mag + two-stage top-64 superset: 448 blocks (28 bf x 16 w).
// Stage 0: mag for the 16-row stripe (frames f,f+1; FROZEN c-chain).
// Stage 1: 4 waves, each finds its 1024-elem 64th-largest (shfl-only) and
// emits enc>=T to a 128-slot LDS range (zero-padded).
// Stage 2 (R18): wave 0 finds Tb = 64th-largest of the <=512 union entries
// == 64th-largest of the block's 4096 (block top-64 is contained in the
// union of wave top-64s), then emits only enc>=Tb to global (~64/block).
__global__ void __launch_bounds__(256) k_magtop(const float* __restrict__ x,
                                                const float* __restrict__ corr,
                                                u64* __restrict__ cand,
                                                u32* __restrict__ wcnt) {
  const int blk = blockIdx.x;        // 448
  const int bf = blk >> 4;
  const int w = blk & 15;
  const int b = bf / NF, f = bf % NF;
  const int tid = threadIdx.x;
  __shared__ float smag[4096];
  __shared__ u64 scand[512];         // 4 waves x 128 slots, zero-padded
  const float cb = corr[b];
  const long long hwbase = (long long)w * 4096;   // 16-row stripe
  const float4* x0 = (const float4*)(x + ((long long)(b * TT + f)) * FRAME + hwbase);
  const float4* x1 = (const float4*)(x + ((long long)(b * TT + f + 1)) * FRAME + hwbase);
  float4 acc[4];
#pragma unroll
  for (int k = 0; k < 4; ++k) acc[k] = make_float4(0.f, 0.f, 0.f, 0.f);
  for (int c = 0; c < CC; ++c) {
    const float4* p0 = x0 + (long long)c * 16384;
    const float4* p1 = x1 + (long long)c * 16384;
    float4 v0[4], v1[4];
#pragma unroll
    for (int k = 0; k < 4; ++k) { v0[k] = p0[k * 256 + tid]; v1[k] = p1[k * 256 + tid]; }
#pragma unroll
    for (int k = 0; k < 4; ++k) {
      acc[k].x = __fadd_rn(acc[k].x, __fadd_rn(__fsub_rn(v1[k].x, v0[k].x), cb));
      acc[k].y = __fadd_rn(acc[k].y, __fadd_rn(__fsub_rn(v1[k].y, v0[k].y), cb));
      acc[k].z = __fadd_rn(acc[k].z, __fadd_rn(__fsub_rn(v1[k].z, v0[k].z), cb));
      acc[k].w = __fadd_rn(acc[k].w, __fadd_rn(__fsub_rn(v1[k].w, v0[k].w), cb));
    }
  }
  // stage at swizzled s-layout + zero the LDS candidate slots
#pragma unroll
  for (int k = 0; k < 4; ++k) {
    int li = (k * 256 + tid) * 4;
    int r = li >> 8, col = li & 255;
    int gl = ((r >> 3) << 5) + (col >> 3);
    int sl = (gl << 6) + ((r & 7) << 3) + (col & 7);
    *(float4*)&smag[sl] = acc[k];
  }
  scand[tid] = 0ull;
  scand[256 + tid] = 0ull;
  __syncthreads();
  // stage 1: per-wave threshold search + LDS emission
  const int lane = tid & 63, wq = tid >> 6;
  const float4* m4 = (const float4*)&smag[wq * 1024];
  u32 e[16];
#pragma unroll
  for (int k = 0; k < 4; ++k) {
    float4 v = m4[k * 64 + lane];
    e[4 * k + 0] = encf(v.x); e[4 * k + 1] = encf(v.y);
    e[4 * k + 2] = encf(v.z); e[4 * k + 3] = encf(v.w);
  }
  u32 T = 0u;
  for (int bit = 31; bit >= 0; --bit) {
    u32 Tt = T | (1u << bit);
    u32 c = 0;
#pragma unroll
    for (int k = 0; k < 16; ++k) c += (e[k] >= Tt) ? 1u : 0u;
#pragma unroll
    for (int off = 1; off < 64; off <<= 1) c += __shfl_xor(c, off, 64);
    if (c >= 64u) T = Tt;
  }
  {
    u32 run = 0;
    const u64 below = (lane == 0) ? 0ull : (~0ull >> (64 - lane));
#pragma unroll
    for (int k = 0; k < 16; ++k) {
      bool cnd = (e[k] >= T);
      u64 mask = __ballot(cnd);
      if (cnd) {
        u32 off = run + (u32)__popcll(mask & below);
        if (off < 128u) {
          int s = (w << 12) + (wq << 10) + ((k >> 2) * 64 + lane) * 4 + (k & 3);
          scand[(wq << 7) + off] = ((u64)e[k] << 32) | (u64)(0xFFFFFFFFu - (u32)s);
        }
      }
      run += (u32)__popcll(mask);
    }
  }
  __syncthreads();
  // stage 2: wave 0 finds Tb over the union and emits enc>=Tb to global
  if (wq == 0) {
    u64 u[8];
    u32 eu[8];
#pragma unroll
    for (int k = 0; k < 8; ++k) {
      u[k] = scand[lane + (k << 6)];
      eu[k] = (u32)(u[k] >> 32);     // pad entries give 0 -> never selected
    }
    u32 Tb = 0u;
    for (int bit = 31; bit >= 0; --bit) {
      u32 Tt = Tb | (1u << bit);
      u32 c = 0;
#pragma unroll
      for (int k = 0; k < 8; ++k) c += (eu[k] >= Tt) ? 1u : 0u;
#pragma unroll
      for (int off = 1; off < 64; off <<= 1) c += __shfl_xor(c, off, 64);
      if (c >= 64u) Tb = Tt;
    }
    u64* dst = cand + (long long)bf * 2048 + w * 128;
    u32 run = 0;
    const u64 below = (lane == 0) ? 0ull : (~0ull >> (64 - lane));
#pragma unroll
    for (int k = 0; k < 8; ++k) {
      bool cnd = (eu[k] >= Tb);
      u64 mask = __ballot(cnd);
      if (cnd) {
        u32 off = run + (u32)__popcll(mask & below);
        if (off < 128u) dst[off] = u[k];
      }
      run += (u32)__popcll(mask);
    }
    if (lane == 0) wcnt[bf * 16 + w] = (run < 128u) ? run : 128u;
  }
}

// ---- fused merge + graph (28 blocks x 1024). R18: back to 16 candidate
// ranges (~64 each). Phase 2: radix-select top-64 on enc hi-32 + fixed
// 64x64 rank. Phases 3-5: FROZEN cov/inv/maha/radix-169.
__global__ void __launch_bounds__(1024) k_merge_graph(const u64* __restrict__ cand,
                                                      const u32* __restrict__ wcnt,
                                                      float* __restrict__ out) {
  const int bf = blockIdx.x;
  const int tid = threadIdx.x;
  __shared__ u64 candk[2048];
  __shared__ u64 sel64[64];
  __shared__ u32 wbase[17];
  __shared__ float cy[64], cx[64];
  __shared__ float sinv[4];
  __shared__ u32 keys[4096];
  __shared__ u32 bins[256 * 32];
  __shared__ u32 stot[256];
  __shared__ u32 tie[4096];
  __shared__ u32 scal[4];

  if (tid < 64) {
    u32 v = (tid < 16) ? wcnt[bf * 16 + tid] : 0u;
#pragma unroll
    for (int off = 1; off < 16; off <<= 1) {
      u32 t = __shfl_up(v, off, 64);
      if ((int)tid - off >= 0) v += t;
    }
    if (tid < 16) wbase[tid + 1] = v;
    if (tid == 0) wbase[0] = 0u;
  }
  __syncthreads();
  {
    int w = tid >> 6, ln = tid & 63;
    u32 cnt = wbase[w + 1] - wbase[w];
    for (u32 s = ln; s < cnt; s += 64)
      candk[wbase[w] + s] = cand[(long long)bf * 2048 + w * 128 + s];
  }
  __syncthreads();
  u32 n = wbase[16];
  if (n > 2048u) n = 2048u;

  // phase 2: radix-select the 64th-largest enc among candidates
  u32 prefix2 = 0u, need2 = 64u;
  for (int pass = 0; pass < 4; ++pass) {
    int shift = 24 - pass * 8;
    for (int i = tid; i < 8192; i += 1024) bins[i] = 0u;
    __syncthreads();
    for (u32 i = tid; i < n; i += 1024) {
      u32 e = (u32)(candk[i] >> 32);
      bool ok = (pass == 0) || ((e >> (shift + 8)) == (prefix2 >> (shift + 8)));
      if (ok) atomicAdd(&bins[(((e >> shift) & 0xFFu) << 5) + (tid & 31)], 1u);
    }
    __syncthreads();
    if (tid < 256) {
      u32 s = 0;
#pragma unroll
      for (int c = 0; c < 32; ++c) s += bins[(tid << 5) + ((c + tid) & 31)];
      stot[tid] = s;
    }
    __syncthreads();
    if (tid < 64) {
      int l = tid;
      u32 t0 = stot[4 * l + 0], t1 = stot[4 * l + 1],
          t2 = stot[4 * l + 2], t3 = stot[4 * l + 3];
      u32 b3 = t3, b2 = t2 + b3, b1 = t1 + b2, b0 = t0 + b1;
      u32 incl = b0;
#pragma unroll
      for (int off = 1; off < 64; off <<= 1) {
        u32 t = __shfl_down(incl, off, 64);
        if (l + off < 64) incl += t;
      }
      u32 excl = incl - b0;
      u32 si0 = b0 + excl, si1 = b1 + excl, si2 = b2 + excl, si3 = b3 + excl;
      if (si0 >= need2 && si1 < need2) { scal[0] = prefix2 | ((u32)(4 * l + 0) << shift); scal[1] = need2 - si1; }
      if (si1 >= need2 && si2 < need2) { scal[0] = prefix2 | ((u32)(4 * l + 1) << shift); scal[1] = need2 - si2; }
      if (si2 >= need2 && si3 < need2) { scal[0] = prefix2 | ((u32)(4 * l + 2) << shift); scal[1] = need2 - si3; }
      if (si3 >= need2 && excl < need2) { scal[0] = prefix2 | ((u32)(4 * l + 3) << shift); scal[1] = need2 - excl; }
    }
    __syncthreads();
    prefix2 = scal[0]; need2 = scal[1];
    __syncthreads();
  }
  if (tid == 0) { scal[2] = 0u; scal[3] = 0u; }
  __syncthreads();
  for (u32 i = tid; i < n; i += 1024) {
    u64 key = candk[i];
    u32 e = (u32)(key >> 32);
    if (e > prefix2) {
      u32 p = atomicAdd(&scal[3], 1u);
      sel64[p] = key;
    } else if (e == prefix2) {
      u32 p = atomicAdd(&scal[2], 1u);
      tie[p] = (u32)(key & 0xFFFFFFFFull);   // ~s (larger = smaller idx)
    }
  }
  __syncthreads();
  {
    int tc2 = (int)scal[2];
    for (int i = tid; i < tc2; i += 1024) {
      u32 mine = tie[i];
      int r = 0, j = 0;
      for (; j + 8 <= tc2; j += 8) {
        u32 a0 = tie[j], a1 = tie[j + 1], a2 = tie[j + 2], a3 = tie[j + 3];
        u32 a4 = tie[j + 4], a5 = tie[j + 5], a6 = tie[j + 6], a7 = tie[j + 7];
        r += (int)(a0 > mine) + (int)(a1 > mine) + (int)(a2 > mine) + (int)(a3 > mine)
           + (int)(a4 > mine) + (int)(a5 > mine) + (int)(a6 > mine) + (int)(a7 > mine);
      }
      for (; j < tc2; ++j) r += (int)(tie[j] > mine);
      if (r < (int)need2) {
        u32 p = atomicAdd(&scal[3], 1u);
        sel64[p] = ((u64)prefix2 << 32) | (u64)mine;
      }
    }
  }
  __syncthreads();
  if (tid < 64) {
    u64 mine = sel64[tid];
    int rank = 0;
#pragma unroll
    for (int j = 0; j < 64; ++j) rank += (sel64[j] > mine) ? 1 : 0;
    int idx = (int)(0xFFFFFFFFu - (u32)(mine & 0xFFFFFFFFull));
    cy[rank] = (float)((idx >> 6) * 8 + 4);
    cx[rank] = (float)((idx & 63) * 8 + 4);
  }
  __syncthreads();

  // mean/cov/inv — FROZEN sequential chains on thread 0
  if (tid == 0) {
    float sy = 0.f, sx = 0.f;
    for (int r = 0; r < 64; ++r) sy = __fadd_rn(sy, cy[r]);
    for (int r = 0; r < 64; ++r) sx = __fadd_rn(sx, cx[r]);
    float my = __fdiv_rn(sy, 64.0f), mx = __fdiv_rn(sx, 64.0f);
    float c00 = 0.f, c01 = 0.f, c11 = 0.f;
    for (int r = 0; r < 64; ++r) {
      float dy = __fsub_rn(cy[r], my);
      float dx = __fsub_rn(cx[r], mx);
      c00 = __fadd_rn(c00, __fmul_rn(dy, dy));
      c01 = __fadd_rn(c01, __fmul_rn(dy, dx));
      c11 = __fadd_rn(c11, __fmul_rn(dx, dx));
    }
    c00 = __fdiv_rn(c00, 63.0f); c01 = __fdiv_rn(c01, 63.0f); c11 = __fdiv_rn(c11, 63.0f);
    c00 = __fadd_rn(c00, 1e-6f); c11 = __fadd_rn(c11, 1e-6f);
    double det = (double)c00 * (double)c11 - (double)c01 * (double)c01;
    sinv[0] = (float)((double)c11 / det);
    sinv[1] = (float)(-(double)c01 / det);
    sinv[2] = sinv[1];
    sinv[3] = (float)((double)c00 / det);
  }
  __syncthreads();

  // maha keys + zero output — FROZEN arithmetic, order-independent
  float i00 = sinv[0], i01 = sinv[1], i10 = sinv[2], i11 = sinv[3];
  long long obase = (long long)bf * 4096;
  for (int ee = tid; ee < 4096; ee += 1024) {
    int q = ee >> 6, r = ee & 63;
    float d0 = __fsub_rn(cy[r], cy[q]);
    float d1 = __fsub_rn(cx[r], cx[q]);
    float v0 = __fadd_rn(__fadd_rn(0.0f, __fmul_rn(d0, i00)), __fmul_rn(d1, i10));
    float v1 = __fadd_rn(__fadd_rn(0.0f, __fmul_rn(d0, i01)), __fmul_rn(d1, i11));
    float p0 = __fmul_rn(v0, d0);
    float p1 = __fmul_rn(v1, d1);
    float s0 = __fsqrt_rn(p0);
    float s1 = __fsqrt_rn(p1);
    float mh = __fadd_rn(__fadd_rn(0.0f, s0), s1);
    u32 key;
    if (mh != mh) key = 0xFFFFFFFFu;   // NaN first (POLICY A, FROZEN)
    else key = encf(-mh);
    keys[ee] = key;
    out[obase + ee] = 0.0f;
  }
  __syncthreads();

  // radix-select top-169: 32-way replicated bins + wave-0 shfl suffix scan
  u32 prefix = 0u, need = 169u;
  for (int pass = 0; pass < 4; ++pass) {
    int shift = 24 - pass * 8;
    if (tid == 0) scal[2] = 0u;
    for (int i = tid; i < 8192; i += 1024) bins[i] = 0u;
    __syncthreads();
    for (int k = 0; k < 4; ++k) {
      u32 ky = keys[tid + (k << 10)];
      bool ok = (pass == 0) || ((ky >> (shift + 8)) == (prefix >> (shift + 8)));
      if (ok) atomicAdd(&bins[(((ky >> shift) & 0xFFu) << 5) + (tid & 31)], 1u);
    }
    __syncthreads();
    if (tid < 256) {
      u32 s = 0;
#pragma unroll
      for (int c = 0; c < 32; ++c) s += bins[(tid << 5) + ((c + tid) & 31)];
      stot[tid] = s;
    }
    __syncthreads();
    if (tid < 64) {
      int l = tid;
      u32 t0 = stot[4 * l + 0], t1 = stot[4 * l + 1],
          t2 = stot[4 * l + 2], t3 = stot[4 * l + 3];
      u32 b3 = t3;
      u32 b2 = t2 + b3;
      u32 b1 = t1 + b2;
      u32 b0 = t0 + b1;
      u32 incl = b0;
#pragma unroll
      for (int off = 1; off < 64; off <<= 1) {
        u32 t = __shfl_down(incl, off, 64);
        if (l + off < 64) incl += t;
      }
      u32 excl = incl - b0;
      u32 si0 = b0 + excl, si1 = b1 + excl, si2 = b2 + excl, si3 = b3 + excl;
      if (si0 >= need && si1 < need) { scal[0] = prefix | ((u32)(4 * l + 0) << shift); scal[1] = need - si1; }
      if (si1 >= need && si2 < need) { scal[0] = prefix | ((u32)(4 * l + 1) << shift); scal[1] = need - si2; }
      if (si2 >= need && si3 < need) { scal[0] = prefix | ((u32)(4 * l + 2) << shift); scal[1] = need - si3; }
      if (si3 >= need && excl < need) { scal[0] = prefix | ((u32)(4 * l + 3) << shift); scal[1] = need - excl; }
    }
    __syncthreads();
    prefix = scal[0]; need = scal[1];
    __syncthreads();
  }
  for (int k = 0; k < 4; ++k) {
    int ee = tid + (k << 10);
    u32 ky = keys[ee];
    if (ky > prefix) out[obase + ee] = 1.0f;
    else if (ky == prefix) {
      u32 p = atomicAdd(&scal[2], 1u);
      tie[p] = (u32)ee;
    }
  }
  __syncthreads();
  int tc = (int)scal[2];
  for (int i = tid; i < tc; i += 1024) {
    u32 ei = tie[i];
    int rank = 0, j = 0;
    for (; j + 8 <= tc; j += 8) {
      u32 a0 = tie[j], a1 = tie[j + 1], a2 = tie[j + 2], a3 = tie[j + 3];
      u32 a4 = tie[j + 4], a5 = tie[j + 5], a6 = tie[j + 6], a7 = tie[j + 7];
      rank += (int)(a0 < ei) + (int)(a1 < ei) + (int)(a2 < ei) + (int)(a3 < ei)
            + (int)(a4 < ei) + (int)(a5 < ei) + (int)(a6 < ei) + (int)(a7 < ei);
    }
    for (; j < tc; ++j) rank += (int)(tie[j] < ei);
    if (rank < (int)need) out[obase + ei] = 1.0f;
  }
}

extern "C" void kernel_launch(void* const* d_in, const int* in_sizes, int n_in,
                              void* d_out, int out_size, void* d_ws, size_t ws_size,
                              hipStream_t stream) {
  if (ws_size < (size_t)WS_NEED) return;
  const float* x = (const float*)d_in[0];
  float* out = (float*)d_out;
  char* ws = (char*)d_ws;
  float* corr = (float*)(ws + WS_CORR);
  u32* wcnt = (u32*)(ws + WS_WCNT);
  u32* mmpart = (u32*)(ws + WS_MMPART);
  u64* cand = (u64*)(ws + WS_CAND);
  u32* histc = (u32*)(ws + WS_HISTC);

  hipLaunchKernelGGL(k_minmax_pass, dim3(2048), dim3(256), 0, stream, x, mmpart);
  hipLaunchKernelGGL(k_hist_pass, dim3(2048), dim3(256), 0, stream, x, mmpart, histc);
  hipLaunchKernelGGL(k_corr, dim3(4), dim3(256), 0, stream, histc, corr);
  hipLaunchKernelGGL(k_magtop, dim3(448), dim3(256), 0, stream, x, corr, cand, wcnt);
  hipLaunchKernelGGL(k_merge_graph, dim3(28), dim3(1024), 0, stream, cand, wcnt, out);
}